// Round 6
// baseline (470.344 us; speedup 1.0000x reference)
//
#include <hip/hip_runtime.h>

#define NIN    20
#define NHID   6
#define NOUT   6
#define BS     256   // threads per block = rows per chunk
#define CHUNKS 4     // chunks per block
#define PAD    22    // even dword stride: 8B-aligned rows -> ds_read_b64; 4-way bank ok

typedef float v2f __attribute__((ext_vector_type(2)));

__device__ __forceinline__ v2f pk_fma(v2f a, v2f b, v2f c) {
#if __has_builtin(__builtin_elementwise_fma)
    return __builtin_elementwise_fma(a, b, c);   // -> v_pk_fma_f32
#else
    v2f r; r.x = fmaf(a.x, b.x, c.x); r.y = fmaf(a.y, b.y, c.y); return r;
#endif
}

__device__ __forceinline__ float fsig(float t) {
    // sigmoid(t) = 1/(1+exp(-t)); v_mul + v_exp + v_add + v_rcp
    return __builtin_amdgcn_rcpf(1.0f + __expf(-t));
}

__global__ __launch_bounds__(BS, 5)
void mlp_fused(const float* __restrict__ x,
               const float* __restrict__ W1,
               const float* __restrict__ W2,
               const float* __restrict__ W5,
               float* __restrict__ out,
               int nrows)
{
    __shared__ float sx[BS * PAD];           // 22528 B

    const int t = threadIdx.x;
    const long long block_row0 = (long long)blockIdx.x * (BS * CHUNKS);

    const v2f* __restrict__ W1v = (const v2f*)W1;   // 10 pairs/row
    const v2f* __restrict__ W2v = (const v2f*)W2;   // 3 pairs/row
    const v2f* __restrict__ W5v = (const v2f*)W5;   // 3 pairs/row

    // ---- prefetch chunk 0 into registers (coalesced: lane stride 16 B) ----
    float4 pre[5];
    {
        const float4* __restrict__ p4 = (const float4*)(x + block_row0 * NIN);
        const long long lim4 = ((long long)nrows - block_row0) * 5;
#pragma unroll
        for (int k = 0; k < 5; ++k) {
            const int i = t + BS * k;
            pre[k] = (i < lim4) ? p4[i] : make_float4(0.f, 0.f, 0.f, 0.f);
        }
    }

#pragma unroll
    for (int c = 0; c < CHUNKS; ++c) {
        const long long chunk_row0 = block_row0 + (long long)c * BS;

        // ---- prefetched regs -> LDS (8B-aligned v2f writes) ----
#pragma unroll
        for (int k = 0; k < 5; ++k) {
            const int i = t + BS * k;        // float4 index within chunk
            const int r = i / 5;
            const int q = (i % 5) * 4;       // even; r*PAD even -> 8B aligned
            v2f* d = (v2f*)&sx[r * PAD + q];
            v2f lo = { pre[k].x, pre[k].y };
            v2f hi = { pre[k].z, pre[k].w };
            d[0] = lo; d[1] = hi;
        }
        __syncthreads();

        // ---- issue NEXT chunk's global loads now (T14: write after barrier) ----
        if (c + 1 < CHUNKS) {
            const long long next_row0 = chunk_row0 + BS;
            const float4* __restrict__ p4 = (const float4*)(x + next_row0 * NIN);
            const long long lim4 = ((long long)nrows - next_row0) * 5;
#pragma unroll
            for (int k = 0; k < 5; ++k) {
                const int i = t + BS * k;
                pre[k] = (i < lim4) ? p4[i] : make_float4(0.f, 0.f, 0.f, 0.f);
            }
        }

        // ---- compute one row per thread, packed-f32 math ----
        const long long row = chunk_row0 + t;
        if (row < nrows) {
            // 10x ds_read_b64
            const v2f* __restrict__ xr2 = (const v2f*)&sx[t * PAD];
            v2f xv[10];
#pragma unroll
            for (int k = 0; k < 10; ++k) xv[k] = xr2[k];

            // layer 1: [20] -> [6], sigmoid. 60 pk_fma + 6 hadd
            float h[NHID];
#pragma unroll
            for (int j = 0; j < NHID; ++j) {
                v2f a = { 0.f, 0.f };
#pragma unroll
                for (int k = 0; k < 10; ++k) a = pk_fma(xv[k], W1v[j * 10 + k], a);
                h[j] = fsig(a.x + a.y);
            }

            // layer 2: [6] -> [6], sigmoid. 18 pk_fma + 6 hadd
            v2f hv[3] = { { h[0], h[1] }, { h[2], h[3] }, { h[4], h[5] } };
            float g[NHID];
#pragma unroll
            for (int j = 0; j < NHID; ++j) {
                v2f a = { 0.f, 0.f };
#pragma unroll
                for (int k = 0; k < 3; ++k) a = pk_fma(hv[k], W2v[j * 3 + k], a);
                g[j] = fsig(a.x + a.y);
            }

            // layer 3: [6] -> [6], linear. 18 pk_fma + 6 hadd
            v2f gv[3] = { { g[0], g[1] }, { g[2], g[3] }, { g[4], g[5] } };
            float o[NOUT];
#pragma unroll
            for (int j = 0; j < NOUT; ++j) {
                v2f a = { 0.f, 0.f };
#pragma unroll
                for (int k = 0; k < 3; ++k) a = pk_fma(gv[k], W5v[j * 3 + k], a);
                o[j] = a.x + a.y;
            }

            // 24 B/row, 8 B-aligned -> 3x 8B stores, dense across the wave
            v2f* __restrict__ op = (v2f*)(out + row * NOUT);
            v2f o0 = { o[0], o[1] }, o1 = { o[2], o[3] }, o2 = { o[4], o[5] };
            op[0] = o0; op[1] = o1; op[2] = o2;
        }

        // all LDS readers done before next iteration overwrites sx
        if (c + 1 < CHUNKS) __syncthreads();
    }
}

extern "C" void kernel_launch(void* const* d_in, const int* in_sizes, int n_in,
                              void* d_out, int out_size, void* d_ws, size_t ws_size,
                              hipStream_t stream) {
    const float* x  = (const float*)d_in[0];
    const float* W1 = (const float*)d_in[1];
    const float* W2 = (const float*)d_in[2];
    const float* W5 = (const float*)d_in[3];
    float* out = (float*)d_out;

    const int nrows = in_sizes[0] / NIN;                             // 4194304
    const int rows_per_block = BS * CHUNKS;                          // 1024
    const int grid = (nrows + rows_per_block - 1) / rows_per_block;  // 4096
    mlp_fused<<<grid, BS, 0, stream>>>(x, W1, W2, W5, out, nrows);
}